// Round 6
// baseline (143.866 us; speedup 1.0000x reference)
//
#include <hip/hip_runtime.h>
#include <math.h>

// Problem constants (fixed by reference)
#define S_LEN   2048
#define HDIM    1024
#define NHEADS  16
#define DHEAD   64
#define BATCH   2
#define MROWS   (BATCH * S_LEN)   // 4096
#define STRIDE  4
#define LOCAL   8
#define NSTRIDED (S_LEN / STRIDE)  // 512

typedef __attribute__((ext_vector_type(8))) _Float16 f16x8;  // 8 fp16 (4 VGPRs)
typedef __attribute__((ext_vector_type(4))) float f32x4;

// ---- fp32 -> fp16 (RN) bit helpers -----------------------------------------
__device__ __forceinline__ unsigned short f16b(float x) {
    _Float16 h = (_Float16)x;
    unsigned short u;
    __builtin_memcpy(&u, &h, 2);
    return u;
}
__device__ __forceinline__ unsigned pack2_f16(float a, float b) {
    return (unsigned)f16b(a) | ((unsigned)f16b(b) << 16);
}

// ---- async global->LDS, 16B per lane (dest = wave base + lane*16) ----------
__device__ __forceinline__ void gll16(const void* g, void* l) {
    __builtin_amdgcn_global_load_lds(
        (const __attribute__((address_space(1))) void*)g,
        (__attribute__((address_space(3))) void*)l, 16, 0, 0);
}

// ---------------------------------------------------------------------------
// Prep 1: x fp32 -> fp16 bits, 4 elems/thread.
// ---------------------------------------------------------------------------
__global__ __launch_bounds__(256)
void xcvt(const float* __restrict__ src, unsigned short* __restrict__ dst, int n4)
{
    const int i = blockIdx.x * 256 + threadIdx.x;
    if (i >= n4) return;
    const float4 v = reinterpret_cast<const float4*>(src)[i];
    reinterpret_cast<ushort4*>(dst)[i] =
        make_ushort4(f16b(v.x), f16b(v.y), f16b(v.z), f16b(v.w));
}

// ---------------------------------------------------------------------------
// Prep 2: weights [K][N] fp32 -> transposed fp16 [N][K]; z picks which of the
// 4 weights; outputs packed contiguously at dst + z*HDIM*HDIM.
// ---------------------------------------------------------------------------
__global__ __launch_bounds__(256)
void wcvt(const float* __restrict__ W0, const float* __restrict__ W1,
          const float* __restrict__ W2, const float* __restrict__ W3,
          unsigned short* __restrict__ dst)
{
    __shared__ unsigned short tile[32][33];
    const int z = blockIdx.z;
    const float* __restrict__ W = (z == 0) ? W0 : (z == 1) ? W1 : (z == 2) ? W2 : W3;
    unsigned short* __restrict__ out = dst + (size_t)z * HDIM * HDIM;
    const int t  = threadIdx.x;
    const int kb = blockIdx.x * 32;
    const int nb = blockIdx.y * 32;
    {
        const int row = t >> 3;          // k within tile
        const int c4  = (t & 7) * 4;     // n within tile
        const float4 v = *reinterpret_cast<const float4*>(
            &W[(size_t)(kb + row) * HDIM + nb + c4]);
        tile[row][c4 + 0] = f16b(v.x);
        tile[row][c4 + 1] = f16b(v.y);
        tile[row][c4 + 2] = f16b(v.z);
        tile[row][c4 + 3] = f16b(v.w);
    }
    __syncthreads();
    {
        const int n  = t >> 3;
        const int k4 = (t & 7) * 4;
        *reinterpret_cast<ushort4*>(&out[(size_t)(nb + n) * HDIM + kb + k4]) =
            make_ushort4(tile[k4][n], tile[k4+1][n], tile[k4+2][n], tile[k4+3][n]);
    }
}

// ---------------------------------------------------------------------------
// fp16 MFMA GEMM, single-term (fp32 accumulate): C = A @ W.
// A: [4096][1024] fp16 bits. W TRANSPOSED [N][K] fp16, z*HDIM*HDIM offset.
// Tile 64x64, BK=64, 16 K-iters, 4 waves (2x2), 2x2 frags/wave.
// LDS 32 KB double-buffered (5 blocks/CU cap); global_load_lds with
// pre-swizzled source; per-iter: stage-next -> compute -> one barrier.
// mode 0 (gridDim.z==3): attention-layout epilogue (z=0 Q scaled, z=1 K+Kp,
// z=2 Vt+Vpt). mode 1: fp32 flat [M][N] + bias.
// ---------------------------------------------------------------------------
__global__ __launch_bounds__(256)
void gemm_f16(const unsigned short* __restrict__ A,
              const unsigned short* __restrict__ Wbase,
              float* __restrict__ C, const float* __restrict__ bias,
              const float* __restrict__ sig_ptr, int mode,
              unsigned short* __restrict__ Qf, unsigned short* __restrict__ Kf,
              unsigned short* __restrict__ Kp, unsigned short* __restrict__ Vt,
              unsigned short* __restrict__ Vpt)
{
    __shared__ unsigned short As[2][64 * 64];
    __shared__ unsigned short Bs[2][64 * 64];

    const int z = blockIdx.z;
    const unsigned short* __restrict__ WT = Wbase + (size_t)z * HDIM * HDIM;

    const int tid  = threadIdx.x;
    const int lane = tid & 63;
    const int w    = tid >> 6;
    const int wr   = w >> 1;      // wave row: 32 rows
    const int wc   = w & 1;       // wave col: 32 cols
    const int row_base = blockIdx.y * 64;
    const int col_base = blockIdx.x * 64;

    f32x4 acc[2][2] = {};

    // stage 64x64 A-tile + 64x64 B-tile; LDS dest linear in chunk id,
    // global source pre-swizzled (row&7 XOR on the 16B slot).
    auto stage = [&](int b, int k0) {
#pragma unroll
        for (int r = 0; r < 2; ++r) {
            const int c    = tid + r * 256;      // chunk 0..511
            const int row  = c >> 3;             // tile row 0..63
            const int c7   = c & 7;              // 16B chunk in 128B row
            const int goff = ((c7 * 16) ^ ((row & 7) << 4)) >> 1;  // f16 elems
            gll16(A  + (size_t)(row_base + row) * HDIM + k0 + goff, &As[b][c * 8]);
            gll16(WT + (size_t)(col_base + row) * HDIM + k0 + goff, &Bs[b][c * 8]);
        }
    };

    auto compute = [&](int b) {
#pragma unroll
        for (int kk = 0; kk < 2; ++kk) {
            const int sofs = (kk * 64 + ((lane >> 4) << 4)) ^ ((lane & 7) << 4);
            f16x8 af[2], bfr[2];
#pragma unroll
            for (int mi = 0; mi < 2; ++mi) {
                const int row = wr * 32 + mi * 16 + (lane & 15);
                af[mi] = *reinterpret_cast<const f16x8*>(
                    reinterpret_cast<const char*>(&As[b][row * 64]) + sofs);
            }
#pragma unroll
            for (int ni = 0; ni < 2; ++ni) {
                const int row = wc * 32 + ni * 16 + (lane & 15);
                bfr[ni] = *reinterpret_cast<const f16x8*>(
                    reinterpret_cast<const char*>(&Bs[b][row * 64]) + sofs);
            }
#pragma unroll
            for (int mi = 0; mi < 2; ++mi)
#pragma unroll
                for (int ni = 0; ni < 2; ++ni)
                    acc[mi][ni] = __builtin_amdgcn_mfma_f32_16x16x32_f16(
                        af[mi], bfr[ni], acc[mi][ni], 0, 0, 0);
        }
    };

    stage(0, 0);
    __syncthreads();
    int buf = 0;
#pragma unroll 1
    for (int kt = 0; kt < 16; ++kt) {
        if (kt + 1 < 16) stage(buf ^ 1, (kt + 1) * 64);
        compute(buf);
        __syncthreads();
        buf ^= 1;
    }

    // ---- epilogue ----
    float scale = 1.0f;
    if (mode == 0 && z == 0) {
        const float u = *sig_ptr;
        scale = (1.0f / (1.0f + __expf(-u))) * 0.125f;  // sigmoid(phi)/sqrt(D)
    }
#pragma unroll
    for (int mi = 0; mi < 2; ++mi) {
#pragma unroll
        for (int ni = 0; ni < 2; ++ni) {
            const int gr0 = row_base + wr * 32 + mi * 16 + ((lane >> 4) << 2);
            const int gc  = col_base + wc * 32 + ni * 16 + (lane & 15);
            if (mode == 0) {
                const int h = gc >> 6, d = gc & 63;
                const int bb = gr0 >> 11;
                const int s0 = gr0 & (S_LEN - 1);       // multiple of 4
                const size_t bh = (size_t)(bb * NHEADS + h);
                if (z == 0) {
#pragma unroll
                    for (int r = 0; r < 4; ++r)
                        Qf[(bh * S_LEN + s0 + r) * DHEAD + d] =
                            f16b(acc[mi][ni][r] * scale);
                } else if (z == 1) {
#pragma unroll
                    for (int r = 0; r < 4; ++r)
                        Kf[(bh * S_LEN + s0 + r) * DHEAD + d] = f16b(acc[mi][ni][r]);
                    Kp[(bh * NSTRIDED + (s0 >> 2)) * DHEAD + d] = f16b(acc[mi][ni][0]);
                } else {
                    ushort4 pv = make_ushort4(f16b(acc[mi][ni][0]), f16b(acc[mi][ni][1]),
                                              f16b(acc[mi][ni][2]), f16b(acc[mi][ni][3]));
                    *reinterpret_cast<ushort4*>(&Vt[(bh * DHEAD + d) * S_LEN + s0]) = pv;
                    Vpt[(bh * DHEAD + d) * NSTRIDED + (s0 >> 2)] = pv.x;
                }
            } else {
                const float bv = bias[gc];
#pragma unroll
                for (int r = 0; r < 4; ++r)
                    C[(size_t)(gr0 + r) * HDIM + gc] = acc[mi][ni][r] + bv;
            }
        }
    }
}

// ---------------------------------------------------------------------------
// MFMA sparse ("strided") flash attention, fp16 inputs, fp32 softmax.
// Block = 4 independent waves; wave owns 16 q-rows. Grid = 2*16*32 = 1024.
// Per 32-key chunk: swapped QK^T (D[key,q], q=lane&15), lane-local online
// softmax, P -> fp16 via per-wave LDS scratch [q][key], swapped PV (D[d,q]).
// 16 strided chunks (packed Kp/Vpt) + 1 masked band chunk ([r0-8, r0+24)).
// No __syncthreads. Output: fp16 [B,S,H] (feeds single-term o-proj).
// ---------------------------------------------------------------------------
__global__ __launch_bounds__(256)
void attn_mfma(const unsigned short* __restrict__ Qf, const unsigned short* __restrict__ Kf,
               const unsigned short* __restrict__ Kp, const unsigned short* __restrict__ Vt,
               const unsigned short* __restrict__ Vpt,
               unsigned short* __restrict__ Of)
{
    __shared__ unsigned short P[4][16][40];   // per-wave [q][key] scratch

    const int tid = threadIdx.x;
    const int L = tid & 63, w = tid >> 6;
    const int c = L & 15, g = L >> 4;
    const int bx = blockIdx.x;
    const int qt = bx & 31;
    const int h  = (bx >> 5) & 15;
    const int b  = bx >> 9;
    const int r0 = qt * 64 + w * 16;
    const size_t bh = (size_t)(b * NHEADS + h);

    const unsigned short* __restrict__ Qb  = Qf  + bh * S_LEN * DHEAD;
    const unsigned short* __restrict__ Kfb = Kf  + bh * S_LEN * DHEAD;
    const unsigned short* __restrict__ Kpb = Kp  + bh * NSTRIDED * DHEAD;
    const unsigned short* __restrict__ Vtb = Vt  + bh * DHEAD * S_LEN;
    const unsigned short* __restrict__ Vpb = Vpt + bh * DHEAD * NSTRIDED;

    // Q B-fragments (held for the whole kernel): q-row = r0+c, d-slices 0/1
    const f16x8 qf0 = *reinterpret_cast<const f16x8*>(&Qb[(r0 + c) * DHEAD + 8 * g]);
    const f16x8 qf1 = *reinterpret_cast<const f16x8*>(&Qb[(r0 + c) * DHEAD + 32 + 8 * g]);

    f32x4 acc[4] = {};            // out[d = dt*16 + 4g + reg][q = c]
    float m = -1e30f, lsum = 0.f;

    char* const Pb = (char*)&P[w][c][0];

    auto chunk = [&](const f16x8 kfr[2][2], const f16x8 vfr[4], bool band, int j0) {
        // ---- QK^T (swapped): D[key, q] ----
        f32x4 sc0 = {}, sc1 = {};
        sc0 = __builtin_amdgcn_mfma_f32_16x16x32_f16(kfr[0][0], qf0, sc0, 0, 0, 0);
        sc0 = __builtin_amdgcn_mfma_f32_16x16x32_f16(kfr[0][1], qf1, sc0, 0, 0, 0);
        sc1 = __builtin_amdgcn_mfma_f32_16x16x32_f16(kfr[1][0], qf0, sc1, 0, 0, 0);
        sc1 = __builtin_amdgcn_mfma_f32_16x16x32_f16(kfr[1][1], qf1, sc1, 0, 0, 0);

        if (band) {
            const int i = r0 + c;
#pragma unroll
            for (int r = 0; r < 4; ++r) {
                const int j = j0 + 4 * g + r;
                const bool ok = (j >= 0) && (j < S_LEN) && ((j & 3) != 0) &&
                                (j >= i - LOCAL) && (j <= i + LOCAL);
                if (!ok) sc0[r] = -1e30f;
            }
#pragma unroll
            for (int r = 0; r < 4; ++r) {
                const int j = j0 + 16 + 4 * g + r;
                const bool ok = (j >= 0) && (j < S_LEN) && ((j & 3) != 0) &&
                                (j >= i - LOCAL) && (j <= i + LOCAL);
                if (!ok) sc1[r] = -1e30f;
            }
        }

        // ---- online softmax (per q = c) ----
        float pmax = fmaxf(fmaxf(fmaxf(sc0[0], sc0[1]), fmaxf(sc0[2], sc0[3])),
                           fmaxf(fmaxf(sc1[0], sc1[1]), fmaxf(sc1[2], sc1[3])));
        pmax = fmaxf(pmax, __shfl_xor(pmax, 16));
        pmax = fmaxf(pmax, __shfl_xor(pmax, 32));
        if (__any(pmax > m + 8.0f)) {          // defer-max: rare, wave-uniform
            const float mn = fmaxf(m, pmax);
            const float f  = __expf(m - mn);
            lsum *= f;
#pragma unroll
            for (int dt = 0; dt < 4; ++dt)
#pragma unroll
                for (int r = 0; r < 4; ++r) acc[dt][r] *= f;
            m = mn;
        }
        float p[8];
#pragma unroll
        for (int r = 0; r < 4; ++r) p[r]     = __expf(sc0[r] - m);
#pragma unroll
        for (int r = 0; r < 4; ++r) p[4 + r] = __expf(sc1[r] - m);
        lsum += ((p[0] + p[1]) + (p[2] + p[3])) + ((p[4] + p[5]) + (p[6] + p[7]));

        // ---- P -> fp16 via per-wave LDS [q][key] (same-wave, no barrier) ----
        *reinterpret_cast<uint2*>(Pb + 8 * g) =
            make_uint2(pack2_f16(p[0], p[1]), pack2_f16(p[2], p[3]));
        *reinterpret_cast<uint2*>(Pb + 32 + 8 * g) =
            make_uint2(pack2_f16(p[4], p[5]), pack2_f16(p[6], p[7]));
        const f16x8 pf = *reinterpret_cast<const f16x8*>(Pb + 16 * g);

        // ---- PV (swapped): D[d, q] ----
#pragma unroll
        for (int dt = 0; dt < 4; ++dt)
            acc[dt] = __builtin_amdgcn_mfma_f32_16x16x32_f16(vfr[dt], pf, acc[dt], 0, 0, 0);
    };

    // ---- 16 strided chunks (512 packed keys) ----
#pragma unroll 2
    for (int kt = 0; kt < 16; ++kt) {
        const int jj0 = kt * 32;
        f16x8 kfr[2][2], vfr[4];
#pragma unroll
        for (int half = 0; half < 2; ++half)
#pragma unroll
            for (int sl = 0; sl < 2; ++sl)
                kfr[half][sl] = *reinterpret_cast<const f16x8*>(
                    &Kpb[(jj0 + half * 16 + c) * DHEAD + sl * 32 + 8 * g]);
#pragma unroll
        for (int dt = 0; dt < 4; ++dt)
            vfr[dt] = *reinterpret_cast<const f16x8*>(
                &Vpb[(dt * 16 + c) * NSTRIDED + jj0 + 8 * g]);
        chunk(kfr, vfr, false, 0);
    }

    // ---- 1 masked band chunk: keys j in [r0-8, r0+24) ----
    {
        const int j0 = r0 - LOCAL;
        f16x8 kfr[2][2], vfr[4];
#pragma unroll
        for (int half = 0; half < 2; ++half) {
            int j = j0 + half * 16 + c;
            j = min(max(j, 0), S_LEN - 1);
#pragma unroll
            for (int sl = 0; sl < 2; ++sl)
                kfr[half][sl] = *reinterpret_cast<const f16x8*>(
                    &Kfb[j * DHEAD + sl * 32 + 8 * g]);
        }
        int js = j0 + 8 * g;
        js = min(max(js, 0), S_LEN - 8);
#pragma unroll
        for (int dt = 0; dt < 4; ++dt)
            vfr[dt] = *reinterpret_cast<const f16x8*>(
                &Vtb[(dt * 16 + c) * S_LEN + js]);
        chunk(kfr, vfr, true, j0);
    }

    // ---- finalize (lane-local in q = c) ----
    lsum += __shfl_xor(lsum, 16);
    lsum += __shfl_xor(lsum, 32);
    const float inv = 1.0f / lsum;
    const int s = r0 + c;
    const size_t ob = ((size_t)(b * S_LEN + s)) * HDIM + h * DHEAD;
#pragma unroll
    for (int dt = 0; dt < 4; ++dt) {
        ushort4 hv = make_ushort4(f16b(acc[dt][0] * inv), f16b(acc[dt][1] * inv),
                                  f16b(acc[dt][2] * inv), f16b(acc[dt][3] * inv));
        *reinterpret_cast<ushort4*>(&Of[ob + dt * 16 + 4 * g]) = hv;
    }
}

// ---------------------------------------------------------------------------
// Pipeline: x->fp16, W->fp16 transposed (batched z=4) -> fused QKV fp16 GEMM
// (z=3, attention layouts) -> MFMA sparse attention (fp16 out) -> o-proj
// fp16 GEMM (+bias, fp32 out).
// Workspace (52 MB): Xf 0-8 | Wall 8-16 (Wq,Wk,Wv,Wo T fp16) | Qf 16-24 |
//                    Kf 24-32 | Kp 32-34 | Vt 34-42 | Vpt 42-44 | Of 44-52.
// ---------------------------------------------------------------------------
extern "C" void kernel_launch(void* const* d_in, const int* in_sizes, int n_in,
                              void* d_out, int out_size, void* d_ws, size_t ws_size,
                              hipStream_t stream)
{
    const float* x      = (const float*)d_in[0];
    const float* q_w    = (const float*)d_in[1];
    const float* k_w    = (const float*)d_in[2];
    const float* v_w    = (const float*)d_in[3];
    const float* o_w    = (const float*)d_in[4];
    const float* o_b    = (const float*)d_in[5];
    const float* uscale = (const float*)d_in[6];
    float* out = (float*)d_out;

    const size_t MB = (size_t)1 << 20;
    char* ws = (char*)d_ws;
    unsigned short* Xf   = (unsigned short*)(ws);
    unsigned short* Wall = (unsigned short*)(ws + 8 * MB);   // 4 x 2MB fp16 [N][K]
    unsigned short* Qf   = (unsigned short*)(ws + 16 * MB);
    unsigned short* Kf   = (unsigned short*)(ws + 24 * MB);
    unsigned short* Kp   = (unsigned short*)(ws + 32 * MB);
    unsigned short* Vt   = (unsigned short*)(ws + 34 * MB);
    unsigned short* Vpt  = (unsigned short*)(ws + 42 * MB);
    unsigned short* Of   = (unsigned short*)(ws + 44 * MB);

    // prep: x and weights to fp16 (weights transposed), one launch each
    xcvt<<<dim3(MROWS * HDIM / 4 / 256), dim3(256), 0, stream>>>(
        x, Xf, MROWS * HDIM / 4);
    wcvt<<<dim3(HDIM / 32, HDIM / 32, 4), dim3(256), 0, stream>>>(
        q_w, k_w, v_w, o_w, Wall);

    // fused QKV projection: z in {0,1,2} -> Q / K(+Kp) / Vt(+Vpt), fp16 out
    const dim3 gg(HDIM / 64, MROWS / 64, 3);   // (16, 64, 3) = 3072 blocks
    gemm_f16<<<gg, dim3(256), 0, stream>>>(Xf, Wall, nullptr, nullptr,
                                           uscale, 0, Qf, Kf, Kp, Vt, Vpt);

    // MFMA sparse attention -> Of (fp16 [B,S,H])
    attn_mfma<<<dim3(BATCH * NHEADS * (S_LEN / 64)), dim3(256), 0, stream>>>(
        Qf, Kf, Kp, Vt, Vpt, Of);

    // output projection + bias (single-term fp16, fp32 out)
    const dim3 go(HDIM / 64, MROWS / 64, 1);   // (16, 64) = 1024 blocks
    gemm_f16<<<go, dim3(256), 0, stream>>>(Of, Wall + 3 * (size_t)HDIM * HDIM,
                                           out, o_b, nullptr, 1,
                                           nullptr, nullptr, nullptr, nullptr, nullptr);
}

// Round 7
// 143.475 us; speedup vs baseline: 1.0027x; 1.0027x over previous
//
#include <hip/hip_runtime.h>
#include <math.h>

// Problem constants (fixed by reference)
#define S_LEN   2048
#define HDIM    1024
#define NHEADS  16
#define DHEAD   64
#define BATCH   2
#define MROWS   (BATCH * S_LEN)   // 4096
#define STRIDE  4
#define LOCAL   8
#define NSTRIDED (S_LEN / STRIDE)  // 512

typedef __attribute__((ext_vector_type(8))) _Float16 f16x8;  // 8 fp16 (4 VGPRs)
typedef __attribute__((ext_vector_type(4))) float f32x4;

// ---- fp32 -> fp16 (RN) bit helpers -----------------------------------------
__device__ __forceinline__ unsigned short f16b(float x) {
    _Float16 h = (_Float16)x;
    unsigned short u;
    __builtin_memcpy(&u, &h, 2);
    return u;
}
__device__ __forceinline__ unsigned pack2_f16(float a, float b) {
    return (unsigned)f16b(a) | ((unsigned)f16b(b) << 16);
}

// ---- async global->LDS, 16B per lane (dest = wave base + lane*16) ----------
__device__ __forceinline__ void gll16(const void* g, void* l) {
    __builtin_amdgcn_global_load_lds(
        (const __attribute__((address_space(1))) void*)g,
        (__attribute__((address_space(3))) void*)l, 16, 0, 0);
}

// ---------------------------------------------------------------------------
// Prep 1: x fp32 -> fp16 bits, 4 elems/thread.
// ---------------------------------------------------------------------------
__global__ __launch_bounds__(256)
void xcvt(const float* __restrict__ src, unsigned short* __restrict__ dst, int n4)
{
    const int i = blockIdx.x * 256 + threadIdx.x;
    if (i >= n4) return;
    const float4 v = reinterpret_cast<const float4*>(src)[i];
    reinterpret_cast<ushort4*>(dst)[i] =
        make_ushort4(f16b(v.x), f16b(v.y), f16b(v.z), f16b(v.w));
}

// ---------------------------------------------------------------------------
// Prep 2: weights [K][N] fp32 -> transposed fp16 [N][K]; z picks which of the
// 4 weights; outputs packed contiguously at dst + z*HDIM*HDIM.
// ---------------------------------------------------------------------------
__global__ __launch_bounds__(256)
void wcvt(const float* __restrict__ W0, const float* __restrict__ W1,
          const float* __restrict__ W2, const float* __restrict__ W3,
          unsigned short* __restrict__ dst)
{
    __shared__ unsigned short tile[32][33];
    const int z = blockIdx.z;
    const float* __restrict__ W = (z == 0) ? W0 : (z == 1) ? W1 : (z == 2) ? W2 : W3;
    unsigned short* __restrict__ out = dst + (size_t)z * HDIM * HDIM;
    const int t  = threadIdx.x;
    const int kb = blockIdx.x * 32;
    const int nb = blockIdx.y * 32;
    {
        const int row = t >> 3;          // k within tile
        const int c4  = (t & 7) * 4;     // n within tile
        const float4 v = *reinterpret_cast<const float4*>(
            &W[(size_t)(kb + row) * HDIM + nb + c4]);
        tile[row][c4 + 0] = f16b(v.x);
        tile[row][c4 + 1] = f16b(v.y);
        tile[row][c4 + 2] = f16b(v.z);
        tile[row][c4 + 3] = f16b(v.w);
    }
    __syncthreads();
    {
        const int n  = t >> 3;
        const int k4 = (t & 7) * 4;
        *reinterpret_cast<ushort4*>(&out[(size_t)(nb + n) * HDIM + kb + k4]) =
            make_ushort4(tile[k4][n], tile[k4+1][n], tile[k4+2][n], tile[k4+3][n]);
    }
}

// ---------------------------------------------------------------------------
// fp16 MFMA GEMM, single-term (fp32 accumulate): C = A @ W.
// A: [4096][1024] fp16 bits. W TRANSPOSED [N][K] fp16, z*HDIM*HDIM offset.
// Tile 64x64, BK=64, 16 K-iters, 4 waves (2x2), 2x2 frags/wave.
// LDS 32 KB double-buffered (5 blocks/CU cap); global_load_lds with
// pre-swizzled source; per-iter: stage-next -> compute -> one barrier.
// mode 0 (gridDim.z==3): attention-layout epilogue (z=0 Q scaled, z=1 K+Kp,
// z=2 Vt+Vpt). mode 1: fp32 flat [M][N] + bias.
// ---------------------------------------------------------------------------
__global__ __launch_bounds__(256)
void gemm_f16(const unsigned short* __restrict__ A,
              const unsigned short* __restrict__ Wbase,
              float* __restrict__ C, const float* __restrict__ bias,
              const float* __restrict__ sig_ptr, int mode,
              unsigned short* __restrict__ Qf, unsigned short* __restrict__ Kf,
              unsigned short* __restrict__ Kp, unsigned short* __restrict__ Vt,
              unsigned short* __restrict__ Vpt)
{
    __shared__ unsigned short As[2][64 * 64];
    __shared__ unsigned short Bs[2][64 * 64];

    const int z = blockIdx.z;
    const unsigned short* __restrict__ WT = Wbase + (size_t)z * HDIM * HDIM;

    const int tid  = threadIdx.x;
    const int lane = tid & 63;
    const int w    = tid >> 6;
    const int wr   = w >> 1;      // wave row: 32 rows
    const int wc   = w & 1;       // wave col: 32 cols
    const int row_base = blockIdx.y * 64;
    const int col_base = blockIdx.x * 64;

    f32x4 acc[2][2] = {};

    // stage 64x64 A-tile + 64x64 B-tile; LDS dest linear in chunk id,
    // global source pre-swizzled (row&7 XOR on the 16B slot).
    auto stage = [&](int b, int k0) {
#pragma unroll
        for (int r = 0; r < 2; ++r) {
            const int c    = tid + r * 256;      // chunk 0..511
            const int row  = c >> 3;             // tile row 0..63
            const int c7   = c & 7;              // 16B chunk in 128B row
            const int goff = ((c7 * 16) ^ ((row & 7) << 4)) >> 1;  // f16 elems
            gll16(A  + (size_t)(row_base + row) * HDIM + k0 + goff, &As[b][c * 8]);
            gll16(WT + (size_t)(col_base + row) * HDIM + k0 + goff, &Bs[b][c * 8]);
        }
    };

    auto compute = [&](int b) {
#pragma unroll
        for (int kk = 0; kk < 2; ++kk) {
            const int sofs = (kk * 64 + ((lane >> 4) << 4)) ^ ((lane & 7) << 4);
            f16x8 af[2], bfr[2];
#pragma unroll
            for (int mi = 0; mi < 2; ++mi) {
                const int row = wr * 32 + mi * 16 + (lane & 15);
                af[mi] = *reinterpret_cast<const f16x8*>(
                    reinterpret_cast<const char*>(&As[b][row * 64]) + sofs);
            }
#pragma unroll
            for (int ni = 0; ni < 2; ++ni) {
                const int row = wc * 32 + ni * 16 + (lane & 15);
                bfr[ni] = *reinterpret_cast<const f16x8*>(
                    reinterpret_cast<const char*>(&Bs[b][row * 64]) + sofs);
            }
#pragma unroll
            for (int mi = 0; mi < 2; ++mi)
#pragma unroll
                for (int ni = 0; ni < 2; ++ni)
                    acc[mi][ni] = __builtin_amdgcn_mfma_f32_16x16x32_f16(
                        af[mi], bfr[ni], acc[mi][ni], 0, 0, 0);
        }
    };

    stage(0, 0);
    __syncthreads();
    int buf = 0;
#pragma unroll 1
    for (int kt = 0; kt < 16; ++kt) {
        if (kt + 1 < 16) stage(buf ^ 1, (kt + 1) * 64);
        compute(buf);
        __syncthreads();
        buf ^= 1;
    }

    // ---- epilogue ----
    float scale = 1.0f;
    if (mode == 0 && z == 0) {
        const float u = *sig_ptr;
        scale = (1.0f / (1.0f + __expf(-u))) * 0.125f;  // sigmoid(phi)/sqrt(D)
    }
#pragma unroll
    for (int mi = 0; mi < 2; ++mi) {
#pragma unroll
        for (int ni = 0; ni < 2; ++ni) {
            const int gr0 = row_base + wr * 32 + mi * 16 + ((lane >> 4) << 2);
            const int gc  = col_base + wc * 32 + ni * 16 + (lane & 15);
            if (mode == 0) {
                const int h = gc >> 6, d = gc & 63;
                const int bb = gr0 >> 11;
                const int s0 = gr0 & (S_LEN - 1);       // multiple of 4
                const size_t bh = (size_t)(bb * NHEADS + h);
                if (z == 0) {
#pragma unroll
                    for (int r = 0; r < 4; ++r)
                        Qf[(bh * S_LEN + s0 + r) * DHEAD + d] =
                            f16b(acc[mi][ni][r] * scale);
                } else if (z == 1) {
#pragma unroll
                    for (int r = 0; r < 4; ++r)
                        Kf[(bh * S_LEN + s0 + r) * DHEAD + d] = f16b(acc[mi][ni][r]);
                    Kp[(bh * NSTRIDED + (s0 >> 2)) * DHEAD + d] = f16b(acc[mi][ni][0]);
                } else {
                    ushort4 pv = make_ushort4(f16b(acc[mi][ni][0]), f16b(acc[mi][ni][1]),
                                              f16b(acc[mi][ni][2]), f16b(acc[mi][ni][3]));
                    *reinterpret_cast<ushort4*>(&Vt[(bh * DHEAD + d) * S_LEN + s0]) = pv;
                    Vpt[(bh * DHEAD + d) * NSTRIDED + (s0 >> 2)] = pv.x;
                }
            } else {
                const float bv = bias[gc];
#pragma unroll
                for (int r = 0; r < 4; ++r)
                    C[(size_t)(gr0 + r) * HDIM + gc] = acc[mi][ni][r] + bv;
            }
        }
    }
}

// ---------------------------------------------------------------------------
// MFMA sparse ("strided") flash attention, fp16 inputs, fp32 softmax.
// Block = 4 independent waves; wave owns 16 q-rows. Grid = 2*16*32 = 1024.
// Per 32-key chunk: swapped QK^T (D[key,q], q=lane&15), lane-local online
// softmax, P -> fp16 via per-wave LDS scratch [q][key], swapped PV (D[d,q]).
// 16 strided chunks (packed Kp/Vpt) + 1 masked band chunk ([r0-8, r0+24)).
// No __syncthreads. Output: fp16 [B,S,H] (feeds single-term o-proj).
// ---------------------------------------------------------------------------
__global__ __launch_bounds__(256)
void attn_mfma(const unsigned short* __restrict__ Qf, const unsigned short* __restrict__ Kf,
               const unsigned short* __restrict__ Kp, const unsigned short* __restrict__ Vt,
               const unsigned short* __restrict__ Vpt,
               unsigned short* __restrict__ Of)
{
    __shared__ unsigned short P[4][16][40];   // per-wave [q][key] scratch

    const int tid = threadIdx.x;
    const int L = tid & 63, w = tid >> 6;
    const int c = L & 15, g = L >> 4;
    const int bx = blockIdx.x;
    const int qt = bx & 31;
    const int h  = (bx >> 5) & 15;
    const int b  = bx >> 9;
    const int r0 = qt * 64 + w * 16;
    const size_t bh = (size_t)(b * NHEADS + h);

    const unsigned short* __restrict__ Qb  = Qf  + bh * S_LEN * DHEAD;
    const unsigned short* __restrict__ Kfb = Kf  + bh * S_LEN * DHEAD;
    const unsigned short* __restrict__ Kpb = Kp  + bh * NSTRIDED * DHEAD;
    const unsigned short* __restrict__ Vtb = Vt  + bh * DHEAD * S_LEN;
    const unsigned short* __restrict__ Vpb = Vpt + bh * DHEAD * NSTRIDED;

    // Q B-fragments (held for the whole kernel): q-row = r0+c, d-slices 0/1
    const f16x8 qf0 = *reinterpret_cast<const f16x8*>(&Qb[(r0 + c) * DHEAD + 8 * g]);
    const f16x8 qf1 = *reinterpret_cast<const f16x8*>(&Qb[(r0 + c) * DHEAD + 32 + 8 * g]);

    f32x4 acc[4] = {};            // out[d = dt*16 + 4g + reg][q = c]
    float m = -1e30f, lsum = 0.f;

    char* const Pb = (char*)&P[w][c][0];

    auto chunk = [&](const f16x8 kfr[2][2], const f16x8 vfr[4], bool band, int j0) {
        // ---- QK^T (swapped): D[key, q] ----
        f32x4 sc0 = {}, sc1 = {};
        sc0 = __builtin_amdgcn_mfma_f32_16x16x32_f16(kfr[0][0], qf0, sc0, 0, 0, 0);
        sc0 = __builtin_amdgcn_mfma_f32_16x16x32_f16(kfr[0][1], qf1, sc0, 0, 0, 0);
        sc1 = __builtin_amdgcn_mfma_f32_16x16x32_f16(kfr[1][0], qf0, sc1, 0, 0, 0);
        sc1 = __builtin_amdgcn_mfma_f32_16x16x32_f16(kfr[1][1], qf1, sc1, 0, 0, 0);

        if (band) {
            const int i = r0 + c;
#pragma unroll
            for (int r = 0; r < 4; ++r) {
                const int j = j0 + 4 * g + r;
                const bool ok = (j >= 0) && (j < S_LEN) && ((j & 3) != 0) &&
                                (j >= i - LOCAL) && (j <= i + LOCAL);
                if (!ok) sc0[r] = -1e30f;
            }
#pragma unroll
            for (int r = 0; r < 4; ++r) {
                const int j = j0 + 16 + 4 * g + r;
                const bool ok = (j >= 0) && (j < S_LEN) && ((j & 3) != 0) &&
                                (j >= i - LOCAL) && (j <= i + LOCAL);
                if (!ok) sc1[r] = -1e30f;
            }
        }

        // ---- online softmax (per q = c) ----
        float pmax = fmaxf(fmaxf(fmaxf(sc0[0], sc0[1]), fmaxf(sc0[2], sc0[3])),
                           fmaxf(fmaxf(sc1[0], sc1[1]), fmaxf(sc1[2], sc1[3])));
        pmax = fmaxf(pmax, __shfl_xor(pmax, 16));
        pmax = fmaxf(pmax, __shfl_xor(pmax, 32));
        if (__any(pmax > m + 8.0f)) {          // defer-max: rare, wave-uniform
            const float mn = fmaxf(m, pmax);
            const float f  = __expf(m - mn);
            lsum *= f;
#pragma unroll
            for (int dt = 0; dt < 4; ++dt)
#pragma unroll
                for (int r = 0; r < 4; ++r) acc[dt][r] *= f;
            m = mn;
        }
        float p[8];
#pragma unroll
        for (int r = 0; r < 4; ++r) p[r]     = __expf(sc0[r] - m);
#pragma unroll
        for (int r = 0; r < 4; ++r) p[4 + r] = __expf(sc1[r] - m);
        lsum += ((p[0] + p[1]) + (p[2] + p[3])) + ((p[4] + p[5]) + (p[6] + p[7]));

        // ---- P -> fp16 via per-wave LDS [q][key] (same-wave, no barrier) ----
        *reinterpret_cast<uint2*>(Pb + 8 * g) =
            make_uint2(pack2_f16(p[0], p[1]), pack2_f16(p[2], p[3]));
        *reinterpret_cast<uint2*>(Pb + 32 + 8 * g) =
            make_uint2(pack2_f16(p[4], p[5]), pack2_f16(p[6], p[7]));
        const f16x8 pf = *reinterpret_cast<const f16x8*>(Pb + 16 * g);

        // ---- PV (swapped): D[d, q] ----
#pragma unroll
        for (int dt = 0; dt < 4; ++dt)
            acc[dt] = __builtin_amdgcn_mfma_f32_16x16x32_f16(vfr[dt], pf, acc[dt], 0, 0, 0);
    };

    // ---- 16 strided chunks (512 packed keys) ----
#pragma unroll 2
    for (int kt = 0; kt < 16; ++kt) {
        const int jj0 = kt * 32;
        f16x8 kfr[2][2], vfr[4];
#pragma unroll
        for (int half = 0; half < 2; ++half)
#pragma unroll
            for (int sl = 0; sl < 2; ++sl)
                kfr[half][sl] = *reinterpret_cast<const f16x8*>(
                    &Kpb[(jj0 + half * 16 + c) * DHEAD + sl * 32 + 8 * g]);
#pragma unroll
        for (int dt = 0; dt < 4; ++dt)
            vfr[dt] = *reinterpret_cast<const f16x8*>(
                &Vpb[(dt * 16 + c) * NSTRIDED + jj0 + 8 * g]);
        chunk(kfr, vfr, false, 0);
    }

    // ---- 1 masked band chunk: keys j in [r0-8, r0+24) ----
    {
        const int j0 = r0 - LOCAL;
        f16x8 kfr[2][2], vfr[4];
#pragma unroll
        for (int half = 0; half < 2; ++half) {
            int j = j0 + half * 16 + c;
            j = min(max(j, 0), S_LEN - 1);
#pragma unroll
            for (int sl = 0; sl < 2; ++sl)
                kfr[half][sl] = *reinterpret_cast<const f16x8*>(
                    &Kfb[j * DHEAD + sl * 32 + 8 * g]);
        }
        int js = j0 + 8 * g;
        js = min(max(js, 0), S_LEN - 8);
#pragma unroll
        for (int dt = 0; dt < 4; ++dt)
            vfr[dt] = *reinterpret_cast<const f16x8*>(
                &Vtb[(dt * 16 + c) * S_LEN + js]);
        chunk(kfr, vfr, true, j0);
    }

    // ---- finalize (lane-local in q = c) ----
    lsum += __shfl_xor(lsum, 16);
    lsum += __shfl_xor(lsum, 32);
    const float inv = 1.0f / lsum;
    const int s = r0 + c;
    const size_t ob = ((size_t)(b * S_LEN + s)) * HDIM + h * DHEAD;
#pragma unroll
    for (int dt = 0; dt < 4; ++dt) {
        ushort4 hv = make_ushort4(f16b(acc[dt][0] * inv), f16b(acc[dt][1] * inv),
                                  f16b(acc[dt][2] * inv), f16b(acc[dt][3] * inv));
        *reinterpret_cast<ushort4*>(&Of[ob + dt * 16 + 4 * g]) = hv;
    }
}

// ---------------------------------------------------------------------------
// Pipeline: x->fp16, W->fp16 transposed (batched z=4) -> fused QKV fp16 GEMM
// (z=3, attention layouts) -> MFMA sparse attention (fp16 out) -> o-proj
// fp16 GEMM (+bias, fp32 out).
// Workspace (52 MB): Xf 0-8 | Wall 8-16 (Wq,Wk,Wv,Wo T fp16) | Qf 16-24 |
//                    Kf 24-32 | Kp 32-34 | Vt 34-42 | Vpt 42-44 | Of 44-52.
// ---------------------------------------------------------------------------
extern "C" void kernel_launch(void* const* d_in, const int* in_sizes, int n_in,
                              void* d_out, int out_size, void* d_ws, size_t ws_size,
                              hipStream_t stream)
{
    const float* x      = (const float*)d_in[0];
    const float* q_w    = (const float*)d_in[1];
    const float* k_w    = (const float*)d_in[2];
    const float* v_w    = (const float*)d_in[3];
    const float* o_w    = (const float*)d_in[4];
    const float* o_b    = (const float*)d_in[5];
    const float* uscale = (const float*)d_in[6];
    float* out = (float*)d_out;

    const size_t MB = (size_t)1 << 20;
    char* ws = (char*)d_ws;
    unsigned short* Xf   = (unsigned short*)(ws);
    unsigned short* Wall = (unsigned short*)(ws + 8 * MB);   // 4 x 2MB fp16 [N][K]
    unsigned short* Qf   = (unsigned short*)(ws + 16 * MB);
    unsigned short* Kf   = (unsigned short*)(ws + 24 * MB);
    unsigned short* Kp   = (unsigned short*)(ws + 32 * MB);
    unsigned short* Vt   = (unsigned short*)(ws + 34 * MB);
    unsigned short* Vpt  = (unsigned short*)(ws + 42 * MB);
    unsigned short* Of   = (unsigned short*)(ws + 44 * MB);

    // prep: x and weights to fp16 (weights transposed), one launch each
    xcvt<<<dim3(MROWS * HDIM / 4 / 256), dim3(256), 0, stream>>>(
        x, Xf, MROWS * HDIM / 4);
    wcvt<<<dim3(HDIM / 32, HDIM / 32, 4), dim3(256), 0, stream>>>(
        q_w, k_w, v_w, o_w, Wall);

    // fused QKV projection: z in {0,1,2} -> Q / K(+Kp) / Vt(+Vpt), fp16 out
    const dim3 gg(HDIM / 64, MROWS / 64, 3);   // (16, 64, 3) = 3072 blocks
    gemm_f16<<<gg, dim3(256), 0, stream>>>(Xf, Wall, nullptr, nullptr,
                                           uscale, 0, Qf, Kf, Kp, Vt, Vpt);

    // MFMA sparse attention -> Of (fp16 [B,S,H])
    attn_mfma<<<dim3(BATCH * NHEADS * (S_LEN / 64)), dim3(256), 0, stream>>>(
        Qf, Kf, Kp, Vt, Vpt, Of);

    // output projection + bias (single-term fp16, fp32 out)
    const dim3 go(HDIM / 64, MROWS / 64, 1);   // (16, 64) = 1024 blocks
    gemm_f16<<<go, dim3(256), 0, stream>>>(Of, Wall + 3 * (size_t)HDIM * HDIM,
                                           out, o_b, nullptr, 1,
                                           nullptr, nullptr, nullptr, nullptr, nullptr);
}

// Round 8
// 143.398 us; speedup vs baseline: 1.0033x; 1.0005x over previous
//
#include <hip/hip_runtime.h>
#include <math.h>

// Problem constants (fixed by reference)
#define S_LEN   2048
#define HDIM    1024
#define NHEADS  16
#define DHEAD   64
#define BATCH   2
#define MROWS   (BATCH * S_LEN)   // 4096
#define STRIDE  4
#define LOCAL   8
#define NSTRIDED (S_LEN / STRIDE)  // 512

typedef __attribute__((ext_vector_type(8))) _Float16 f16x8;  // 8 fp16 (4 VGPRs)
typedef __attribute__((ext_vector_type(4))) float f32x4;

// ---- fp32 -> fp16 (RN) bit helpers -----------------------------------------
__device__ __forceinline__ unsigned short f16b(float x) {
    _Float16 h = (_Float16)x;
    unsigned short u;
    __builtin_memcpy(&u, &h, 2);
    return u;
}
__device__ __forceinline__ unsigned pack2_f16(float a, float b) {
    return (unsigned)f16b(a) | ((unsigned)f16b(b) << 16);
}

// ---- async global->LDS, 16B per lane (dest = wave base + lane*16) ----------
__device__ __forceinline__ void gll16(const void* g, void* l) {
    __builtin_amdgcn_global_load_lds(
        (const __attribute__((address_space(1))) void*)g,
        (__attribute__((address_space(3))) void*)l, 16, 0, 0);
}

// ---------------------------------------------------------------------------
// Prep 1: x fp32 -> fp16 bits, 4 elems/thread.
// ---------------------------------------------------------------------------
__global__ __launch_bounds__(256)
void xcvt(const float* __restrict__ src, unsigned short* __restrict__ dst, int n4)
{
    const int i = blockIdx.x * 256 + threadIdx.x;
    if (i >= n4) return;
    const float4 v = reinterpret_cast<const float4*>(src)[i];
    reinterpret_cast<ushort4*>(dst)[i] =
        make_ushort4(f16b(v.x), f16b(v.y), f16b(v.z), f16b(v.w));
}

// ---------------------------------------------------------------------------
// Prep 2: weights [K][N] fp32 -> transposed fp16 [N][K]; z picks which of the
// 4 weights; outputs packed contiguously at dst + z*HDIM*HDIM.
// ---------------------------------------------------------------------------
__global__ __launch_bounds__(256)
void wcvt(const float* __restrict__ W0, const float* __restrict__ W1,
          const float* __restrict__ W2, const float* __restrict__ W3,
          unsigned short* __restrict__ dst)
{
    __shared__ unsigned short tile[32][33];
    const int z = blockIdx.z;
    const float* __restrict__ W = (z == 0) ? W0 : (z == 1) ? W1 : (z == 2) ? W2 : W3;
    unsigned short* __restrict__ out = dst + (size_t)z * HDIM * HDIM;
    const int t  = threadIdx.x;
    const int kb = blockIdx.x * 32;
    const int nb = blockIdx.y * 32;
    {
        const int row = t >> 3;          // k within tile
        const int c4  = (t & 7) * 4;     // n within tile
        const float4 v = *reinterpret_cast<const float4*>(
            &W[(size_t)(kb + row) * HDIM + nb + c4]);
        tile[row][c4 + 0] = f16b(v.x);
        tile[row][c4 + 1] = f16b(v.y);
        tile[row][c4 + 2] = f16b(v.z);
        tile[row][c4 + 3] = f16b(v.w);
    }
    __syncthreads();
    {
        const int n  = t >> 3;
        const int k4 = (t & 7) * 4;
        *reinterpret_cast<ushort4*>(&out[(size_t)(nb + n) * HDIM + kb + k4]) =
            make_ushort4(tile[k4][n], tile[k4+1][n], tile[k4+2][n], tile[k4+3][n]);
    }
}

// ---------------------------------------------------------------------------
// fp16 MFMA GEMM, single-term (fp32 accumulate): C = A @ W.
// A: [4096][1024] fp16 bits. W TRANSPOSED [N][K] fp16, z*HDIM*HDIM offset.
// Tile 64x64, BK=64, 16 K-iters, 4 waves (2x2), 2x2 frags/wave.
// LDS 32 KB double-buffered (5 blocks/CU cap); global_load_lds with
// pre-swizzled source; per-iter: stage-next -> compute -> one barrier.
// mode 0 (gridDim.z==3): attention-layout epilogue (z=0 Q scaled, z=1 K+Kp,
// z=2 Vt+Vpt). mode 1: fp32 flat [M][N] + bias.
// ---------------------------------------------------------------------------
__global__ __launch_bounds__(256)
void gemm_f16(const unsigned short* __restrict__ A,
              const unsigned short* __restrict__ Wbase,
              float* __restrict__ C, const float* __restrict__ bias,
              const float* __restrict__ sig_ptr, int mode,
              unsigned short* __restrict__ Qf, unsigned short* __restrict__ Kf,
              unsigned short* __restrict__ Kp, unsigned short* __restrict__ Vt,
              unsigned short* __restrict__ Vpt)
{
    __shared__ unsigned short As[2][64 * 64];
    __shared__ unsigned short Bs[2][64 * 64];

    const int z = blockIdx.z;
    const unsigned short* __restrict__ WT = Wbase + (size_t)z * HDIM * HDIM;

    const int tid  = threadIdx.x;
    const int lane = tid & 63;
    const int w    = tid >> 6;
    const int wr   = w >> 1;      // wave row: 32 rows
    const int wc   = w & 1;       // wave col: 32 cols
    const int row_base = blockIdx.y * 64;
    const int col_base = blockIdx.x * 64;

    f32x4 acc[2][2] = {};

    // stage 64x64 A-tile + 64x64 B-tile; LDS dest linear in chunk id,
    // global source pre-swizzled (row&7 XOR on the 16B slot).
    auto stage = [&](int b, int k0) {
#pragma unroll
        for (int r = 0; r < 2; ++r) {
            const int c    = tid + r * 256;      // chunk 0..511
            const int row  = c >> 3;             // tile row 0..63
            const int c7   = c & 7;              // 16B chunk in 128B row
            const int goff = ((c7 * 16) ^ ((row & 7) << 4)) >> 1;  // f16 elems
            gll16(A  + (size_t)(row_base + row) * HDIM + k0 + goff, &As[b][c * 8]);
            gll16(WT + (size_t)(col_base + row) * HDIM + k0 + goff, &Bs[b][c * 8]);
        }
    };

    auto compute = [&](int b) {
#pragma unroll
        for (int kk = 0; kk < 2; ++kk) {
            const int sofs = (kk * 64 + ((lane >> 4) << 4)) ^ ((lane & 7) << 4);
            f16x8 af[2], bfr[2];
#pragma unroll
            for (int mi = 0; mi < 2; ++mi) {
                const int row = wr * 32 + mi * 16 + (lane & 15);
                af[mi] = *reinterpret_cast<const f16x8*>(
                    reinterpret_cast<const char*>(&As[b][row * 64]) + sofs);
            }
#pragma unroll
            for (int ni = 0; ni < 2; ++ni) {
                const int row = wc * 32 + ni * 16 + (lane & 15);
                bfr[ni] = *reinterpret_cast<const f16x8*>(
                    reinterpret_cast<const char*>(&Bs[b][row * 64]) + sofs);
            }
#pragma unroll
            for (int mi = 0; mi < 2; ++mi)
#pragma unroll
                for (int ni = 0; ni < 2; ++ni)
                    acc[mi][ni] = __builtin_amdgcn_mfma_f32_16x16x32_f16(
                        af[mi], bfr[ni], acc[mi][ni], 0, 0, 0);
        }
    };

    stage(0, 0);
    __syncthreads();
    int buf = 0;
#pragma unroll 1
    for (int kt = 0; kt < 16; ++kt) {
        if (kt + 1 < 16) stage(buf ^ 1, (kt + 1) * 64);
        compute(buf);
        __syncthreads();
        buf ^= 1;
    }

    // ---- epilogue ----
    float scale = 1.0f;
    if (mode == 0 && z == 0) {
        const float u = *sig_ptr;
        scale = (1.0f / (1.0f + __expf(-u))) * 0.125f;  // sigmoid(phi)/sqrt(D)
    }
#pragma unroll
    for (int mi = 0; mi < 2; ++mi) {
#pragma unroll
        for (int ni = 0; ni < 2; ++ni) {
            const int gr0 = row_base + wr * 32 + mi * 16 + ((lane >> 4) << 2);
            const int gc  = col_base + wc * 32 + ni * 16 + (lane & 15);
            if (mode == 0) {
                const int h = gc >> 6, d = gc & 63;
                const int bb = gr0 >> 11;
                const int s0 = gr0 & (S_LEN - 1);       // multiple of 4
                const size_t bh = (size_t)(bb * NHEADS + h);
                if (z == 0) {
#pragma unroll
                    for (int r = 0; r < 4; ++r)
                        Qf[(bh * S_LEN + s0 + r) * DHEAD + d] =
                            f16b(acc[mi][ni][r] * scale);
                } else if (z == 1) {
#pragma unroll
                    for (int r = 0; r < 4; ++r)
                        Kf[(bh * S_LEN + s0 + r) * DHEAD + d] = f16b(acc[mi][ni][r]);
                    Kp[(bh * NSTRIDED + (s0 >> 2)) * DHEAD + d] = f16b(acc[mi][ni][0]);
                } else {
                    ushort4 pv = make_ushort4(f16b(acc[mi][ni][0]), f16b(acc[mi][ni][1]),
                                              f16b(acc[mi][ni][2]), f16b(acc[mi][ni][3]));
                    *reinterpret_cast<ushort4*>(&Vt[(bh * DHEAD + d) * S_LEN + s0]) = pv;
                    Vpt[(bh * DHEAD + d) * NSTRIDED + (s0 >> 2)] = pv.x;
                }
            } else {
                const float bv = bias[gc];
#pragma unroll
                for (int r = 0; r < 4; ++r)
                    C[(size_t)(gr0 + r) * HDIM + gc] = acc[mi][ni][r] + bv;
            }
        }
    }
}

// ---------------------------------------------------------------------------
// MFMA sparse ("strided") flash attention, fp16 inputs, fp32 softmax.
// Block = 4 independent waves; wave owns 16 q-rows. Grid = 2*16*32 = 1024.
// Per 32-key chunk: swapped QK^T (D[key,q], q=lane&15), lane-local online
// softmax, P -> fp16 via per-wave LDS scratch [q][key], swapped PV (D[d,q]).
// 16 strided chunks (packed Kp/Vpt) + 1 masked band chunk ([r0-8, r0+24)).
// No __syncthreads. Output: fp16 [B,S,H] (feeds single-term o-proj).
// ---------------------------------------------------------------------------
__global__ __launch_bounds__(256)
void attn_mfma(const unsigned short* __restrict__ Qf, const unsigned short* __restrict__ Kf,
               const unsigned short* __restrict__ Kp, const unsigned short* __restrict__ Vt,
               const unsigned short* __restrict__ Vpt,
               unsigned short* __restrict__ Of)
{
    __shared__ unsigned short P[4][16][40];   // per-wave [q][key] scratch

    const int tid = threadIdx.x;
    const int L = tid & 63, w = tid >> 6;
    const int c = L & 15, g = L >> 4;
    const int bx = blockIdx.x;
    const int qt = bx & 31;
    const int h  = (bx >> 5) & 15;
    const int b  = bx >> 9;
    const int r0 = qt * 64 + w * 16;
    const size_t bh = (size_t)(b * NHEADS + h);

    const unsigned short* __restrict__ Qb  = Qf  + bh * S_LEN * DHEAD;
    const unsigned short* __restrict__ Kfb = Kf  + bh * S_LEN * DHEAD;
    const unsigned short* __restrict__ Kpb = Kp  + bh * NSTRIDED * DHEAD;
    const unsigned short* __restrict__ Vtb = Vt  + bh * DHEAD * S_LEN;
    const unsigned short* __restrict__ Vpb = Vpt + bh * DHEAD * NSTRIDED;

    // Q B-fragments (held for the whole kernel): q-row = r0+c, d-slices 0/1
    const f16x8 qf0 = *reinterpret_cast<const f16x8*>(&Qb[(r0 + c) * DHEAD + 8 * g]);
    const f16x8 qf1 = *reinterpret_cast<const f16x8*>(&Qb[(r0 + c) * DHEAD + 32 + 8 * g]);

    f32x4 acc[4] = {};            // out[d = dt*16 + 4g + reg][q = c]
    float m = -1e30f, lsum = 0.f;

    char* const Pb = (char*)&P[w][c][0];

    auto chunk = [&](const f16x8 kfr[2][2], const f16x8 vfr[4], bool band, int j0) {
        // ---- QK^T (swapped): D[key, q] ----
        f32x4 sc0 = {}, sc1 = {};
        sc0 = __builtin_amdgcn_mfma_f32_16x16x32_f16(kfr[0][0], qf0, sc0, 0, 0, 0);
        sc0 = __builtin_amdgcn_mfma_f32_16x16x32_f16(kfr[0][1], qf1, sc0, 0, 0, 0);
        sc1 = __builtin_amdgcn_mfma_f32_16x16x32_f16(kfr[1][0], qf0, sc1, 0, 0, 0);
        sc1 = __builtin_amdgcn_mfma_f32_16x16x32_f16(kfr[1][1], qf1, sc1, 0, 0, 0);

        if (band) {
            const int i = r0 + c;
#pragma unroll
            for (int r = 0; r < 4; ++r) {
                const int j = j0 + 4 * g + r;
                const bool ok = (j >= 0) && (j < S_LEN) && ((j & 3) != 0) &&
                                (j >= i - LOCAL) && (j <= i + LOCAL);
                if (!ok) sc0[r] = -1e30f;
            }
#pragma unroll
            for (int r = 0; r < 4; ++r) {
                const int j = j0 + 16 + 4 * g + r;
                const bool ok = (j >= 0) && (j < S_LEN) && ((j & 3) != 0) &&
                                (j >= i - LOCAL) && (j <= i + LOCAL);
                if (!ok) sc1[r] = -1e30f;
            }
        }

        // ---- online softmax (per q = c) ----
        float pmax = fmaxf(fmaxf(fmaxf(sc0[0], sc0[1]), fmaxf(sc0[2], sc0[3])),
                           fmaxf(fmaxf(sc1[0], sc1[1]), fmaxf(sc1[2], sc1[3])));
        pmax = fmaxf(pmax, __shfl_xor(pmax, 16));
        pmax = fmaxf(pmax, __shfl_xor(pmax, 32));
        if (__any(pmax > m + 8.0f)) {          // defer-max: rare, wave-uniform
            const float mn = fmaxf(m, pmax);
            const float f  = __expf(m - mn);
            lsum *= f;
#pragma unroll
            for (int dt = 0; dt < 4; ++dt)
#pragma unroll
                for (int r = 0; r < 4; ++r) acc[dt][r] *= f;
            m = mn;
        }
        float p[8];
#pragma unroll
        for (int r = 0; r < 4; ++r) p[r]     = __expf(sc0[r] - m);
#pragma unroll
        for (int r = 0; r < 4; ++r) p[4 + r] = __expf(sc1[r] - m);
        lsum += ((p[0] + p[1]) + (p[2] + p[3])) + ((p[4] + p[5]) + (p[6] + p[7]));

        // ---- P -> fp16 via per-wave LDS [q][key] (same-wave, no barrier) ----
        *reinterpret_cast<uint2*>(Pb + 8 * g) =
            make_uint2(pack2_f16(p[0], p[1]), pack2_f16(p[2], p[3]));
        *reinterpret_cast<uint2*>(Pb + 32 + 8 * g) =
            make_uint2(pack2_f16(p[4], p[5]), pack2_f16(p[6], p[7]));
        const f16x8 pf = *reinterpret_cast<const f16x8*>(Pb + 16 * g);

        // ---- PV (swapped): D[d, q] ----
#pragma unroll
        for (int dt = 0; dt < 4; ++dt)
            acc[dt] = __builtin_amdgcn_mfma_f32_16x16x32_f16(vfr[dt], pf, acc[dt], 0, 0, 0);
    };

    // ---- 16 strided chunks (512 packed keys) ----
#pragma unroll 2
    for (int kt = 0; kt < 16; ++kt) {
        const int jj0 = kt * 32;
        f16x8 kfr[2][2], vfr[4];
#pragma unroll
        for (int half = 0; half < 2; ++half)
#pragma unroll
            for (int sl = 0; sl < 2; ++sl)
                kfr[half][sl] = *reinterpret_cast<const f16x8*>(
                    &Kpb[(jj0 + half * 16 + c) * DHEAD + sl * 32 + 8 * g]);
#pragma unroll
        for (int dt = 0; dt < 4; ++dt)
            vfr[dt] = *reinterpret_cast<const f16x8*>(
                &Vpb[(dt * 16 + c) * NSTRIDED + jj0 + 8 * g]);
        chunk(kfr, vfr, false, 0);
    }

    // ---- 1 masked band chunk: keys j in [r0-8, r0+24) ----
    {
        const int j0 = r0 - LOCAL;
        f16x8 kfr[2][2], vfr[4];
#pragma unroll
        for (int half = 0; half < 2; ++half) {
            int j = j0 + half * 16 + c;
            j = min(max(j, 0), S_LEN - 1);
#pragma unroll
            for (int sl = 0; sl < 2; ++sl)
                kfr[half][sl] = *reinterpret_cast<const f16x8*>(
                    &Kfb[j * DHEAD + sl * 32 + 8 * g]);
        }
        int js = j0 + 8 * g;
        js = min(max(js, 0), S_LEN - 8);
#pragma unroll
        for (int dt = 0; dt < 4; ++dt)
            vfr[dt] = *reinterpret_cast<const f16x8*>(
                &Vtb[(dt * 16 + c) * S_LEN + js]);
        chunk(kfr, vfr, true, j0);
    }

    // ---- finalize (lane-local in q = c) ----
    lsum += __shfl_xor(lsum, 16);
    lsum += __shfl_xor(lsum, 32);
    const float inv = 1.0f / lsum;
    const int s = r0 + c;
    const size_t ob = ((size_t)(b * S_LEN + s)) * HDIM + h * DHEAD;
#pragma unroll
    for (int dt = 0; dt < 4; ++dt) {
        ushort4 hv = make_ushort4(f16b(acc[dt][0] * inv), f16b(acc[dt][1] * inv),
                                  f16b(acc[dt][2] * inv), f16b(acc[dt][3] * inv));
        *reinterpret_cast<ushort4*>(&Of[ob + dt * 16 + 4 * g]) = hv;
    }
}

// ---------------------------------------------------------------------------
// Pipeline: x->fp16, W->fp16 transposed (batched z=4) -> fused QKV fp16 GEMM
// (z=3, attention layouts) -> MFMA sparse attention (fp16 out) -> o-proj
// fp16 GEMM (+bias, fp32 out).
// Workspace (52 MB): Xf 0-8 | Wall 8-16 (Wq,Wk,Wv,Wo T fp16) | Qf 16-24 |
//                    Kf 24-32 | Kp 32-34 | Vt 34-42 | Vpt 42-44 | Of 44-52.
// ---------------------------------------------------------------------------
extern "C" void kernel_launch(void* const* d_in, const int* in_sizes, int n_in,
                              void* d_out, int out_size, void* d_ws, size_t ws_size,
                              hipStream_t stream)
{
    const float* x      = (const float*)d_in[0];
    const float* q_w    = (const float*)d_in[1];
    const float* k_w    = (const float*)d_in[2];
    const float* v_w    = (const float*)d_in[3];
    const float* o_w    = (const float*)d_in[4];
    const float* o_b    = (const float*)d_in[5];
    const float* uscale = (const float*)d_in[6];
    float* out = (float*)d_out;

    const size_t MB = (size_t)1 << 20;
    char* ws = (char*)d_ws;
    unsigned short* Xf   = (unsigned short*)(ws);
    unsigned short* Wall = (unsigned short*)(ws + 8 * MB);   // 4 x 2MB fp16 [N][K]
    unsigned short* Qf   = (unsigned short*)(ws + 16 * MB);
    unsigned short* Kf   = (unsigned short*)(ws + 24 * MB);
    unsigned short* Kp   = (unsigned short*)(ws + 32 * MB);
    unsigned short* Vt   = (unsigned short*)(ws + 34 * MB);
    unsigned short* Vpt  = (unsigned short*)(ws + 42 * MB);
    unsigned short* Of   = (unsigned short*)(ws + 44 * MB);

    // prep: x and weights to fp16 (weights transposed), one launch each
    xcvt<<<dim3(MROWS * HDIM / 4 / 256), dim3(256), 0, stream>>>(
        x, Xf, MROWS * HDIM / 4);
    wcvt<<<dim3(HDIM / 32, HDIM / 32, 4), dim3(256), 0, stream>>>(
        q_w, k_w, v_w, o_w, Wall);

    // fused QKV projection: z in {0,1,2} -> Q / K(+Kp) / Vt(+Vpt), fp16 out
    const dim3 gg(HDIM / 64, MROWS / 64, 3);   // (16, 64, 3) = 3072 blocks
    gemm_f16<<<gg, dim3(256), 0, stream>>>(Xf, Wall, nullptr, nullptr,
                                           uscale, 0, Qf, Kf, Kp, Vt, Vpt);

    // MFMA sparse attention -> Of (fp16 [B,S,H])
    attn_mfma<<<dim3(BATCH * NHEADS * (S_LEN / 64)), dim3(256), 0, stream>>>(
        Qf, Kf, Kp, Vt, Vpt, Of);

    // output projection + bias (single-term fp16, fp32 out)
    const dim3 go(HDIM / 64, MROWS / 64, 1);   // (16, 64) = 1024 blocks
    gemm_f16<<<go, dim3(256), 0, stream>>>(Of, Wall + 3 * (size_t)HDIM * HDIM,
                                           out, o_b, nullptr, 1,
                                           nullptr, nullptr, nullptr, nullptr, nullptr);
}